// Round 11
// baseline (42.933 us; speedup 1.0000x reference)
//
#include <hip/hip_runtime.h>
#include <hip/hip_bf16.h>

typedef __attribute__((ext_vector_type(8))) short bf16x8;
typedef __attribute__((ext_vector_type(4))) float f32x4;
typedef __attribute__((ext_vector_type(16))) float f32x16;
typedef __attribute__((ext_vector_type(2))) unsigned int u32x2;
typedef unsigned short u16;
typedef unsigned int u32;

#define EMB 128
#define LOG2E 1.44269504088896f

// round-to-nearest-even fp32 -> bf16
static __device__ __forceinline__ u16 f2bf(float f) {
    union { float f; u32 u; } v; v.f = f;
    u32 u = v.u;
    return (u16)((u + 0x7FFFu + ((u >> 16) & 1u)) >> 16);
}

static __device__ __forceinline__ u32 cvtpk(float a, float b) {
    u32 r;
    asm("v_cvt_pk_bf16_f32 %0, %1, %2" : "=v"(r) : "v"(a), "v"(b));
    return r;
}

static __device__ __forceinline__ float vexp2(float x) {
    float r;
    asm("v_exp_f32 %0, %1" : "=v"(r) : "v"(x));
    return r;
}

// exchange: a' = [a.lo32 | b.lo32(partner)], b' = [a.hi32(partner) | b.hi32]
static __device__ __forceinline__ void plswap(u32& a, u32& b) {
#if __has_builtin(__builtin_amdgcn_permlane32_swap)
    u32x2 r = __builtin_amdgcn_permlane32_swap(a, b, false, false);
    a = r[0]; b = r[1];
#else
    u32 sa = __shfl_xor(a, 32), sb = __shfl_xor(b, 32);
    bool hi = (threadIdx.x & 32) != 0;
    u32 na = hi ? sb : a;
    u32 nb = hi ? b : sa;
    a = na; b = nb;
#endif
}

// Verified half-P-transform: 8 f32 regs of a 32x32 D tile (rows (r&3)+8*(r>>2)
// +4*hi2 within a 16-row band) + bias, scale -> bf16x8 fragment with
// (lane = col, element e = row hi2*8+e).
static __device__ __forceinline__ bf16x8 xform8(float d0, float d1, float d2,
        float d3, float d4, float d5, float d6, float d7,
        float4 bA, float4 bB, float scale) {
    u32 x0 = cvtpk((d0 + bA.x) * scale, (d1 + bA.y) * scale);
    u32 x1 = cvtpk((d2 + bA.z) * scale, (d3 + bA.w) * scale);
    u32 y0 = cvtpk((d4 + bB.x) * scale, (d5 + bB.y) * scale);
    u32 y1 = cvtpk((d6 + bB.z) * scale, (d7 + bB.w) * scale);
    plswap(x0, y0);
    plswap(x1, y1);
    union { u32 w[4]; bf16x8 v; } r;
    r.w[0] = x0; r.w[1] = x1; r.w[2] = y0; r.w[3] = y1;
    return r.v;
}

// ---------------------------------------------------------------------------
// Weight prep: wt[mat][n][k] = bf16(w[mat][k][n]), mat: q,k,v,o
__global__ void __launch_bounds__(256) k_prep(const float* __restrict__ wq,
        const float* __restrict__ wk, const float* __restrict__ wv,
        const float* __restrict__ wo, u16* __restrict__ wt) {
    int i = blockIdx.x * 256 + threadIdx.x;
    int mat = i >> 14, rem = i & 16383;
    int k = rem >> 7, n = rem & 127;
    const float* src = mat == 0 ? wq : mat == 1 ? wk : mat == 2 ? wv : wo;
    wt[mat * 16384 + n * 128 + k] = f2bf(src[rem]);
}

// ---------------------------------------------------------------------------
// Fused LN -> QKV -> attention -> out-proj. Block = (seq row, q-half):
// 512 blocks, 512 threads = 8 waves = 8 heads. KQ produced together by one
// dup-MFMA chain (A rows 0-15 = Wk head rows, 16-31 = Wq head rows); V
// chains interleaved. LDS (68 KB -> 2 blocks/CU):
//   [0,     34816)  Xs : LN'd X, [128 tok][136 u16]  (reused as ctxs)
//   [34816, 69632)  Vs : [8 h][16 d][136 tok-pitch] u16
__global__ void __launch_bounds__(512, 4) k_fused(const float* __restrict__ pe,
        const float* __restrict__ g, const float* __restrict__ bia,
        const u16* __restrict__ wt,
        const float* __restrict__ bq, const float* __restrict__ bk,
        const float* __restrict__ bv, const float* __restrict__ bo,
        const float* __restrict__ mask, float* __restrict__ out) {
    __shared__ __align__(16) char smem[69632];
    u16* Xs = reinterpret_cast<u16*>(smem);            // pitch 136
    u16* Vs = reinterpret_cast<u16*>(smem + 34816);
    char* ctxs = smem;                                  // 256B-pitch, swizzled

    int tid = threadIdx.x;
    int bx = blockIdx.x;
    int seq = bx >> 1, qh = bx & 1;
    int lane = tid & 63, h = tid >> 6;
    int lo = lane & 15, hi4 = lane >> 4;
    int lo2 = lane & 31, hi2 = lane >> 5;

    // ---- Preload weights/biases (L2) — latency hides under LN's HBM reads.
    // KQ-interleaved A rows: lane row r=lo2: r<16 -> Wk d=r; r>=16 -> Wq d=r-16.
    const u16* wrow = (lo2 < 16) ? (wt + 16384 + (h * 16 + lo2) * 128)
                                 : (wt + (h * 16 + (lo2 - 16)) * 128);
    bf16x8 wf[8];
#pragma unroll
    for (int kk = 0; kk < 8; ++kk)
        wf[kk] = *reinterpret_cast<const bf16x8*>(wrow + kk * 16 + hi2 * 8);
    bf16x8 bfv[4];
#pragma unroll
    for (int kk = 0; kk < 4; ++kk)
        bfv[kk] = *reinterpret_cast<const bf16x8*>(
            wt + 2 * 16384 + (h * 16 + lo) * 128 + kk * 32 + hi4 * 8);
    float4 bkA = *reinterpret_cast<const float4*>(bk + h * 16 + hi2 * 4);
    float4 bkB = *reinterpret_cast<const float4*>(bk + h * 16 + 8 + hi2 * 4);
    float4 bqA = *reinterpret_cast<const float4*>(bq + h * 16 + hi2 * 4);
    float4 bqB = *reinterpret_cast<const float4*>(bq + h * 16 + 8 + hi2 * 4);
    float bv_ = bv[h * 16 + lo];

    // ---- Phase 1: LayerNorm, 4 threads/token, 128 tokens (r10 verbatim) ----
    {
        int tl = tid >> 2;
        int q = tid & 3;
        const float4* src = reinterpret_cast<const float4*>(pe + (size_t)(seq * 128 + tl) * EMB);
        float4 v[8];
        float s = 0.f, ss = 0.f;
#pragma unroll
        for (int i = 0; i < 8; ++i) {
            v[i] = src[i * 4 + q];
            s += v[i].x + v[i].y + v[i].z + v[i].w;
            ss += v[i].x * v[i].x + v[i].y * v[i].y + v[i].z * v[i].z + v[i].w * v[i].w;
        }
        s += __shfl_xor(s, 1); ss += __shfl_xor(ss, 1);
        s += __shfl_xor(s, 2); ss += __shfl_xor(ss, 2);
        float mean = s * (1.f / EMB);
        float var = ss * (1.f / EMB) - mean * mean;
        float rstd = rsqrtf(var + 1e-5f);
#pragma unroll
        for (int i = 0; i < 8; ++i) {
            int c = i * 16 + q * 4;
            float4 gg = *reinterpret_cast<const float4*>(g + c);
            float4 bb = *reinterpret_cast<const float4*>(bia + c);
            uint2 packed;
            packed.x = (u32)f2bf((v[i].x - mean) * rstd * gg.x + bb.x)
                     | ((u32)f2bf((v[i].y - mean) * rstd * gg.y + bb.y) << 16);
            packed.y = (u32)f2bf((v[i].z - mean) * rstd * gg.z + bb.z)
                     | ((u32)f2bf((v[i].w - mean) * rstd * gg.w + bb.w) << 16);
            *reinterpret_cast<uint2*>(&Xs[tl * 136 + c]) = packed;
        }
    }
    __syncthreads();

    // ---- Phase 2: KQ dup-chain + V 16x16 chains, interleaved per t-tile ----
    bf16x8 kf[4], qf[2];
#pragma unroll
    for (int t = 0; t < 4; ++t) {
        f32x16 acc = {};
#pragma unroll
        for (int kk = 0; kk < 8; ++kk) {
            bf16x8 xf = *reinterpret_cast<const bf16x8*>(
                &Xs[(t * 32 + lo2) * 136 + kk * 16 + hi2 * 8]);
            acc = __builtin_amdgcn_mfma_f32_32x32x16_bf16(wf[kk], xf, acc, 0, 0, 0);
        }
        kf[t] = xform8(acc[0], acc[1], acc[2], acc[3], acc[4], acc[5], acc[6], acc[7],
                       bkA, bkB, 1.0f);
        if ((t >> 1) == qh)
            qf[t & 1] = xform8(acc[8], acc[9], acc[10], acc[11], acc[12], acc[13],
                               acc[14], acc[15], bqA, bqB, 0.25f);
        // V subs 2t, 2t+1 — independent chains, interleave with KQ chain
#pragma unroll
        for (int s2 = 0; s2 < 2; ++s2) {
            int sub = t * 2 + s2;
            f32x4 av = {};
#pragma unroll
            for (int kk2 = 0; kk2 < 4; ++kk2) {
                bf16x8 a = *reinterpret_cast<const bf16x8*>(
                    &Xs[(sub * 16 + lo) * 136 + kk2 * 32 + hi4 * 8]);
                av = __builtin_amdgcn_mfma_f32_16x16x32_bf16(a, bfv[kk2], av, 0, 0, 0);
            }
            int tokv = sub * 16 + hi4 * 4;
            uint2 pv;
            pv.x = cvtpk(av[0] + bv_, av[1] + bv_);
            pv.y = cvtpk(av[2] + bv_, av[3] + bv_);
            *reinterpret_cast<uint2*>(&Vs[h * 2176 + lo * 136 + tokv]) = pv;
        }
    }
    __syncthreads();   // Xs dead for all waves -> reuse as ctxs; Vs ordered

    // ---- Phase 3: attention (kf/qf in regs, V from LDS), 2 q-tiles ----
    const f32x16 zero = {};
#pragma unroll
    for (int ql = 0; ql < 2; ++ql) {
        f32x16 s[4];
        __builtin_amdgcn_s_setprio(1);
#pragma unroll
        for (int t = 0; t < 4; ++t)
            s[t] = __builtin_amdgcn_mfma_f32_32x32x16_bf16(kf[t], qf[ql], zero, 0, 0, 0);
        __builtin_amdgcn_s_setprio(0);

        // tree max (depth ~6) instead of serial 63-chain
        float mA[16];
#pragma unroll
        for (int i = 0; i < 16; ++i)
            mA[i] = fmaxf(fmaxf(s[0][i], s[1][i]), fmaxf(s[2][i], s[3][i]));
#pragma unroll
        for (int i = 0; i < 8; ++i) mA[i] = fmaxf(mA[i], mA[i + 8]);
#pragma unroll
        for (int i = 0; i < 4; ++i) mA[i] = fmaxf(mA[i], mA[i + 4]);
        float m = fmaxf(fmaxf(mA[0], mA[1]), fmaxf(mA[2], mA[3]));
        m = fmaxf(m, __shfl_xor(m, 32));
        float m2 = m * LOG2E;

        // exp(s-m) = 2^(s*log2e - m2): one FMA + one v_exp per element
        float sm[4] = {0.f, 0.f, 0.f, 0.f};
#pragma unroll
        for (int t = 0; t < 4; ++t)
#pragma unroll
            for (int r = 0; r < 16; ++r) {
                float p = vexp2(__builtin_fmaf(s[t][r], LOG2E, -m2));
                s[t][r] = p;
                sm[t] += p;
            }
        float sum = (sm[0] + sm[1]) + (sm[2] + sm[3]);
        sum += __shfl_xor(sum, 32);
        float inv = 1.f / sum;

        // P -> bf16 fragments (verified transform)
        bf16x8 pb[8];
#pragma unroll
        for (int c = 0; c < 8; ++c) {
            int t = c >> 1, hf = (c & 1) * 8;
            u32 x0 = cvtpk(s[t][hf + 0], s[t][hf + 1]);
            u32 x1 = cvtpk(s[t][hf + 2], s[t][hf + 3]);
            u32 y0 = cvtpk(s[t][hf + 4], s[t][hf + 5]);
            u32 y1 = cvtpk(s[t][hf + 6], s[t][hf + 7]);
            plswap(x0, y0);
            plswap(x1, y1);
            union { u32 wd[4]; bf16x8 v; } pbu;
            pbu.wd[0] = x0; pbu.wd[1] = x1; pbu.wd[2] = y0; pbu.wd[3] = y1;
            pb[c] = pbu.v;
        }

        // PV: two independent accumulator chains
        f32x16 o0 = {}, o1 = {};
        __builtin_amdgcn_s_setprio(1);
#pragma unroll
        for (int c = 0; c < 8; ++c) {
            bf16x8 va = *reinterpret_cast<const bf16x8*>(
                &Vs[h * 2176 + lo * 136 + c * 16 + hi2 * 8]);
            if (c & 1)
                o1 = __builtin_amdgcn_mfma_f32_32x32x16_bf16(va, pb[c], o1, 0, 0, 0);
            else
                o0 = __builtin_amdgcn_mfma_f32_32x32x16_bf16(va, pb[c], o0, 0, 0, 0);
        }
        __builtin_amdgcn_s_setprio(0);

        int tok = ql * 32 + lo2;   // local token row 0..63
        u32 off0 = (u32)(tok * 256 + h * 32 + 8 * hi2) ^ ((tok & 7) << 4);
        u32 off1 = (u32)(tok * 256 + h * 32 + 16 + 8 * hi2) ^ ((tok & 7) << 4);
        uint2 p0, p1;
        p0.x = cvtpk((o0[0] + o1[0]) * inv, (o0[1] + o1[1]) * inv);
        p0.y = cvtpk((o0[2] + o1[2]) * inv, (o0[3] + o1[3]) * inv);
        p1.x = cvtpk((o0[4] + o1[4]) * inv, (o0[5] + o1[5]) * inv);
        p1.y = cvtpk((o0[6] + o1[6]) * inv, (o0[7] + o1[7]) * inv);
        *reinterpret_cast<uint2*>(ctxs + off0) = p0;
        *reinterpret_cast<uint2*>(ctxs + off1) = p1;
    }
    __syncthreads();

    // ---- Phase 4: out-proj for own 64 tokens (r10 verbatim) ----
    {
        int grp = h >> 1, ch = h & 1;
        const u16* wo = wt + 3 * 16384;
        f32x4 acc[4];
#pragma unroll
        for (int c = 0; c < 4; ++c) acc[c] = f32x4{0.f, 0.f, 0.f, 0.f};
#pragma unroll
        for (int kk = 0; kk < 4; ++kk) {
            int tokrow = grp * 16 + lo;
            u32 aoff = (u32)(tokrow * 256 + kk * 64 + hi4 * 16) ^ ((tokrow & 7) << 4);
            bf16x8 a = *reinterpret_cast<const bf16x8*>(ctxs + aoff);
#pragma unroll
            for (int c = 0; c < 4; ++c) {
                bf16x8 b = *reinterpret_cast<const bf16x8*>(
                    wo + (ch * 64 + c * 16 + lo) * 128 + kk * 32 + hi4 * 8);
                acc[c] = __builtin_amdgcn_mfma_f32_16x16x32_bf16(a, b, acc[c], 0, 0, 0);
            }
        }
#pragma unroll
        for (int c = 0; c < 4; ++c) {
            int col = ch * 64 + c * 16 + lo;
            float bval = bo[col];
#pragma unroll
            for (int j = 0; j < 4; ++j) {
                int t = seq * 128 + qh * 64 + grp * 16 + hi4 * 4 + j;
                out[(size_t)t * EMB + col] = (acc[c][j] + bval) * mask[t];
            }
        }
    }
}

// ---------------------------------------------------------------------------
extern "C" void kernel_launch(void* const* d_in, const int* in_sizes, int n_in,
                              void* d_out, int out_size, void* d_ws, size_t ws_size,
                              hipStream_t stream) {
    const float* pe   = (const float*)d_in[0];
    const float* mask = (const float*)d_in[1];
    const float* ln_g = (const float*)d_in[2];
    const float* ln_b = (const float*)d_in[3];
    const float* wq   = (const float*)d_in[4];
    const float* bq   = (const float*)d_in[5];
    const float* wk   = (const float*)d_in[6];
    const float* bk   = (const float*)d_in[7];
    const float* wv   = (const float*)d_in[8];
    const float* bv   = (const float*)d_in[9];
    const float* wo   = (const float*)d_in[10];
    const float* bo   = (const float*)d_in[11];
    float* out = (float*)d_out;

    u16* wt = (u16*)d_ws;            // 4 x [n][k] bf16 = 128 KB

    hipLaunchKernelGGL(k_prep,  dim3(256), dim3(256), 0, stream, wq, wk, wv, wo, wt);
    hipLaunchKernelGGL(k_fused, dim3(512), dim3(512), 0, stream, pe, ln_g, ln_b, wt,
                       bq, bk, bv, bo, mask, out);
}

// Round 12
// 35.748 us; speedup vs baseline: 1.2010x; 1.2010x over previous
//
#include <hip/hip_runtime.h>
#include <hip/hip_bf16.h>

typedef __attribute__((ext_vector_type(8))) short bf16x8;
typedef __attribute__((ext_vector_type(4))) float f32x4;
typedef __attribute__((ext_vector_type(16))) float f32x16;
typedef __attribute__((ext_vector_type(2))) unsigned int u32x2;
typedef unsigned short u16;
typedef unsigned int u32;

#define EMB 128
#define LOG2E 1.44269504088896f

// round-to-nearest-even fp32 -> bf16
static __device__ __forceinline__ u16 f2bf(float f) {
    union { float f; u32 u; } v; v.f = f;
    u32 u = v.u;
    return (u16)((u + 0x7FFFu + ((u >> 16) & 1u)) >> 16);
}

static __device__ __forceinline__ u32 cvtpk(float a, float b) {
    u32 r;
    asm("v_cvt_pk_bf16_f32 %0, %1, %2" : "=v"(r) : "v"(a), "v"(b));
    return r;
}

static __device__ __forceinline__ float vexp2(float x) {
    float r;
    asm("v_exp_f32 %0, %1" : "=v"(r) : "v"(x));
    return r;
}

// exchange: a' = [a.lo32 | b.lo32(partner)], b' = [a.hi32(partner) | b.hi32]
static __device__ __forceinline__ void plswap(u32& a, u32& b) {
#if __has_builtin(__builtin_amdgcn_permlane32_swap)
    u32x2 r = __builtin_amdgcn_permlane32_swap(a, b, false, false);
    a = r[0]; b = r[1];
#else
    u32 sa = __shfl_xor(a, 32), sb = __shfl_xor(b, 32);
    bool hi = (threadIdx.x & 32) != 0;
    u32 na = hi ? sb : a;
    u32 nb = hi ? b : sa;
    a = na; b = nb;
#endif
}

// ---------------------------------------------------------------------------
// Weight prep: wt[mat][n][k] = bf16(w[mat][k][n]), mat: q,k,v,o
__global__ void __launch_bounds__(256) k_prep(const float* __restrict__ wq,
        const float* __restrict__ wk, const float* __restrict__ wv,
        const float* __restrict__ wo, u16* __restrict__ wt) {
    int i = blockIdx.x * 256 + threadIdx.x;
    int mat = i >> 14, rem = i & 16383;
    int k = rem >> 7, n = rem & 127;
    const float* src = mat == 0 ? wq : mat == 1 ? wk : mat == 2 ? wv : wo;
    wt[mat * 16384 + n * 128 + k] = f2bf(src[rem]);
}

// ---------------------------------------------------------------------------
// Fully fused: LN -> QKV (LDS) -> attention -> out-proj. One block per seq
// row (256 blocks = 256 CUs), 512 threads = 8 waves = 8 heads.
// r9 structure; deltas: early W preload (r5-proven), tree-max, exp2-FMA.
// LDS map (132 KB):
//   [0,      34816)  Xs   : LN'd X, [128 tok][136 u16]  (reused as ctxs)
//   [34816,  67584)  Qs   : [8 h][128 tok][16 d] u16, XOR-swz idx^((tok&4)<<1)
//   [67584, 100352)  Ks   : same as Qs
//   [100352,135168)  Vs   : [8 h][16 d][136 tok-pitch] u16
__global__ void __launch_bounds__(512) k_fused(const float* __restrict__ pe,
        const float* __restrict__ g, const float* __restrict__ bia,
        const u16* __restrict__ wt,
        const float* __restrict__ bq, const float* __restrict__ bk,
        const float* __restrict__ bv, const float* __restrict__ bo,
        const float* __restrict__ mask, float* __restrict__ out) {
    __shared__ __align__(16) char smem[135168];
    u16* Xs = reinterpret_cast<u16*>(smem);            // pitch 136
    u16* Qs = reinterpret_cast<u16*>(smem + 34816);
    u16* Ks = reinterpret_cast<u16*>(smem + 67584);
    u16* Vs = reinterpret_cast<u16*>(smem + 100352);
    char* ctxs = smem;                                  // 256B-pitch, swizzled

    int tid = threadIdx.x;
    int seq = blockIdx.x;
    int lane = tid & 63, h = tid >> 6;
    int lo = lane & 15, hi = lane >> 4;

    // ---- W fragments + biases preloaded before LN (L2 latency hides) ----
    bf16x8 bf[3][4];
#pragma unroll
    for (int mat = 0; mat < 3; ++mat)
#pragma unroll
        for (int kk = 0; kk < 4; ++kk)
            bf[mat][kk] = *reinterpret_cast<const bf16x8*>(
                wt + mat * 16384 + (h * 16 + lo) * 128 + kk * 32 + hi * 8);
    float4 bq4 = *reinterpret_cast<const float4*>(bq + h * 16 + hi * 4);
    float4 bk4 = *reinterpret_cast<const float4*>(bk + h * 16 + hi * 4);
    float bv_ = bv[h * 16 + lo];

    // ---- Phase 1: LayerNorm, 4 threads/token, 128 tokens ----
    {
        int tl = tid >> 2;
        int q = tid & 3;
        const float4* src = reinterpret_cast<const float4*>(pe + (size_t)(seq * 128 + tl) * EMB);
        float4 v[8];
        float s = 0.f, ss = 0.f;
#pragma unroll
        for (int i = 0; i < 8; ++i) {
            v[i] = src[i * 4 + q];
            s += v[i].x + v[i].y + v[i].z + v[i].w;
            ss += v[i].x * v[i].x + v[i].y * v[i].y + v[i].z * v[i].z + v[i].w * v[i].w;
        }
        s += __shfl_xor(s, 1); ss += __shfl_xor(ss, 1);
        s += __shfl_xor(s, 2); ss += __shfl_xor(ss, 2);
        float mean = s * (1.f / EMB);
        float var = ss * (1.f / EMB) - mean * mean;
        float rstd = rsqrtf(var + 1e-5f);
#pragma unroll
        for (int i = 0; i < 8; ++i) {
            int c = i * 16 + q * 4;
            float4 gg = *reinterpret_cast<const float4*>(g + c);
            float4 bb = *reinterpret_cast<const float4*>(bia + c);
            uint2 packed;
            packed.x = (u32)f2bf((v[i].x - mean) * rstd * gg.x + bb.x)
                     | ((u32)f2bf((v[i].y - mean) * rstd * gg.y + bb.y) << 16);
            packed.y = (u32)f2bf((v[i].z - mean) * rstd * gg.z + bb.z)
                     | ((u32)f2bf((v[i].w - mean) * rstd * gg.w + bb.w) << 16);
            *reinterpret_cast<uint2*>(&Xs[tl * 136 + c]) = packed;
        }
    }
    __syncthreads();

    // ---- Phase 2: per-head QKV GEMM (W in regs) -> LDS ----
    {
#pragma unroll
        for (int sub = 0; sub < 8; ++sub) {
            bf16x8 a[4];
#pragma unroll
            for (int kk = 0; kk < 4; ++kk)
                a[kk] = *reinterpret_cast<const bf16x8*>(&Xs[(sub * 16 + lo) * 136 + kk * 32 + hi * 8]);
            f32x4 aq = {}, ak = {}, av = {};
#pragma unroll
            for (int kk = 0; kk < 4; ++kk) {
                // swapped: D col = token = lo, row = d = hi*4+j
                aq = __builtin_amdgcn_mfma_f32_16x16x32_bf16(bf[0][kk], a[kk], aq, 0, 0, 0);
                ak = __builtin_amdgcn_mfma_f32_16x16x32_bf16(bf[1][kk], a[kk], ak, 0, 0, 0);
                // normal: D col = d = lo, row = token = hi*4+j
                av = __builtin_amdgcn_mfma_f32_16x16x32_bf16(a[kk], bf[2][kk], av, 0, 0, 0);
            }
            // Q/K packed write: token = sub*16+lo, d = hi*4..hi*4+3
            {
                int tok = sub * 16 + lo;
                int idx = ((h << 11) + tok * 16 + hi * 4) ^ ((tok & 4) << 1);
                uint2 pq, pk;
                pq.x = (u32)f2bf((aq[0] + bq4.x) * 0.25f) | ((u32)f2bf((aq[1] + bq4.y) * 0.25f) << 16);
                pq.y = (u32)f2bf((aq[2] + bq4.z) * 0.25f) | ((u32)f2bf((aq[3] + bq4.w) * 0.25f) << 16);
                pk.x = (u32)f2bf(ak[0] + bk4.x) | ((u32)f2bf(ak[1] + bk4.y) << 16);
                pk.y = (u32)f2bf(ak[2] + bk4.z) | ((u32)f2bf(ak[3] + bk4.w) << 16);
                *reinterpret_cast<uint2*>(&Qs[idx]) = pq;
                *reinterpret_cast<uint2*>(&Ks[idx]) = pk;
            }
            // V packed write: [d=lo][tok], tok = sub*16 + hi*4 + j
            {
                int tokv = sub * 16 + hi * 4;
                uint2 pv;
                pv.x = (u32)f2bf(av[0] + bv_) | ((u32)f2bf(av[1] + bv_) << 16);
                pv.y = (u32)f2bf(av[2] + bv_) | ((u32)f2bf(av[3] + bv_) << 16);
                *reinterpret_cast<uint2*>(&Vs[h * 2176 + lo * 136 + tokv]) = pv;
            }
        }
    }
    __syncthreads();

    // ---- Phase 3: attention (reads Qs/Ks/Vs; writes ctxs = Xs region) ----
    {
        int lo2 = lane & 31, hi2 = lane >> 5;
        int swz = (lo2 & 4) << 1;            // tok&4 == lo2&4 for tok = t*32+lo2
        const f32x16 zero = {};

        bf16x8 kf[4];
#pragma unroll
        for (int t = 0; t < 4; ++t)
            kf[t] = *reinterpret_cast<const bf16x8*>(
                &Ks[(h << 11) + (((t * 32 + lo2) * 16 + hi2 * 8) ^ swz)]);

        for (int qt = 0; qt < 4; ++qt) {
            bf16x8 qf = *reinterpret_cast<const bf16x8*>(
                &Qs[(h << 11) + (((qt * 32 + lo2) * 16 + hi2 * 8) ^ swz)]);
            f32x16 s[4];
#pragma unroll
            for (int t = 0; t < 4; ++t)
                s[t] = __builtin_amdgcn_mfma_f32_32x32x16_bf16(kf[t], qf, zero, 0, 0, 0);

            // tree max (depth ~6) instead of 63-deep serial chain
            float mA[16];
#pragma unroll
            for (int i = 0; i < 16; ++i)
                mA[i] = fmaxf(fmaxf(s[0][i], s[1][i]), fmaxf(s[2][i], s[3][i]));
#pragma unroll
            for (int i = 0; i < 8; ++i) mA[i] = fmaxf(mA[i], mA[i + 8]);
#pragma unroll
            for (int i = 0; i < 4; ++i) mA[i] = fmaxf(mA[i], mA[i + 4]);
            float m = fmaxf(fmaxf(mA[0], mA[1]), fmaxf(mA[2], mA[3]));
            m = fmaxf(m, __shfl_xor(m, 32));
            float m2 = m * LOG2E;

            // exp(s-m) = 2^(s*log2e - m2): one FMA + one v_exp per element
            float sm0 = 0.f, sm1 = 0.f, sm2 = 0.f, sm3 = 0.f;
#pragma unroll
            for (int t = 0; t < 4; ++t)
#pragma unroll
                for (int r = 0; r < 16; ++r) {
                    float p = vexp2(__builtin_fmaf(s[t][r], LOG2E, -m2));
                    s[t][r] = p;
                    if (t == 0) sm0 += p; else if (t == 1) sm1 += p;
                    else if (t == 2) sm2 += p; else sm3 += p;
                }
            float sum = (sm0 + sm1) + (sm2 + sm3);
            sum += __shfl_xor(sum, 32);
            float inv = 1.f / sum;

            f32x16 o = {};
#pragma unroll
            for (int c = 0; c < 8; ++c) {
                int t = c >> 1, hf = (c & 1) * 8;
                u32 x0 = cvtpk(s[t][hf + 0], s[t][hf + 1]);
                u32 x1 = cvtpk(s[t][hf + 2], s[t][hf + 3]);
                u32 y0 = cvtpk(s[t][hf + 4], s[t][hf + 5]);
                u32 y1 = cvtpk(s[t][hf + 6], s[t][hf + 7]);
                plswap(x0, y0);
                plswap(x1, y1);
                union { u32 wd[4]; bf16x8 v; } pb;
                pb.wd[0] = x0; pb.wd[1] = x1; pb.wd[2] = y0; pb.wd[3] = y1;
                bf16x8 va = *reinterpret_cast<const bf16x8*>(
                    &Vs[h * 2176 + (lo2 & 15) * 136 + c * 16 + hi2 * 8]);
                o = __builtin_amdgcn_mfma_f32_32x32x16_bf16(va, pb.v, o, 0, 0, 0);
            }

            int tok = qt * 32 + lo2;
            u32 off0 = (u32)(tok * 256 + h * 32 + 8 * hi2) ^ ((tok & 7) << 4);
            u32 off1 = (u32)(tok * 256 + h * 32 + 16 + 8 * hi2) ^ ((tok & 7) << 4);
            uint2 p0, p1;
            p0.x = (u32)f2bf(o[0] * inv) | ((u32)f2bf(o[1] * inv) << 16);
            p0.y = (u32)f2bf(o[2] * inv) | ((u32)f2bf(o[3] * inv) << 16);
            p1.x = (u32)f2bf(o[4] * inv) | ((u32)f2bf(o[5] * inv) << 16);
            p1.y = (u32)f2bf(o[6] * inv) | ((u32)f2bf(o[7] * inv) << 16);
            *reinterpret_cast<uint2*>(ctxs + off0) = p0;
            *reinterpret_cast<uint2*>(ctxs + off1) = p1;
        }
    }
    __syncthreads();

    // ---- Phase 4: out-proj; wave h does tokens [h*16, h*16+16) ----
    {
        const u16* wo = wt + 3 * 16384;
        f32x4 acc[8];
#pragma unroll
        for (int c = 0; c < 8; ++c) acc[c] = f32x4{0.f, 0.f, 0.f, 0.f};
#pragma unroll
        for (int kk = 0; kk < 4; ++kk) {
            int tokrow = h * 16 + lo;
            u32 aoff = (u32)(tokrow * 256 + kk * 64 + hi * 16) ^ ((tokrow & 7) << 4);
            bf16x8 a = *reinterpret_cast<const bf16x8*>(ctxs + aoff);
#pragma unroll
            for (int c = 0; c < 8; ++c) {
                bf16x8 b = *reinterpret_cast<const bf16x8*>(wo + (c * 16 + lo) * 128 + kk * 32 + hi * 8);
                acc[c] = __builtin_amdgcn_mfma_f32_16x16x32_bf16(a, b, acc[c], 0, 0, 0);
            }
        }
#pragma unroll
        for (int c = 0; c < 8; ++c) {
            int col = c * 16 + lo;
            float bval = bo[col];
#pragma unroll
            for (int j = 0; j < 4; ++j) {
                int t = seq * 128 + h * 16 + hi * 4 + j;
                out[(size_t)t * EMB + col] = (acc[c][j] + bval) * mask[t];
            }
        }
    }
}

// ---------------------------------------------------------------------------
extern "C" void kernel_launch(void* const* d_in, const int* in_sizes, int n_in,
                              void* d_out, int out_size, void* d_ws, size_t ws_size,
                              hipStream_t stream) {
    const float* pe   = (const float*)d_in[0];
    const float* mask = (const float*)d_in[1];
    const float* ln_g = (const float*)d_in[2];
    const float* ln_b = (const float*)d_in[3];
    const float* wq   = (const float*)d_in[4];
    const float* bq   = (const float*)d_in[5];
    const float* wk   = (const float*)d_in[6];
    const float* bk   = (const float*)d_in[7];
    const float* wv   = (const float*)d_in[8];
    const float* bv   = (const float*)d_in[9];
    const float* wo   = (const float*)d_in[10];
    const float* bo   = (const float*)d_in[11];
    float* out = (float*)d_out;

    u16* wt = (u16*)d_ws;            // 4 x [n][k] bf16 = 128 KB

    hipLaunchKernelGGL(k_prep,  dim3(256), dim3(256), 0, stream, wq, wk, wv, wo, wt);
    hipLaunchKernelGGL(k_fused, dim3(256), dim3(512), 0, stream, pe, ln_g, ln_b, wt,
                       bq, bk, bv, bo, mask, out);
}

// Round 14
// 35.659 us; speedup vs baseline: 1.2040x; 1.0025x over previous
//
#include <hip/hip_runtime.h>
#include <hip/hip_bf16.h>

typedef __attribute__((ext_vector_type(8))) short bf16x8;
typedef __attribute__((ext_vector_type(4))) float f32x4;
typedef __attribute__((ext_vector_type(16))) float f32x16;
typedef __attribute__((ext_vector_type(2))) unsigned int u32x2;
typedef unsigned short u16;
typedef unsigned int u32;

#define EMB 128
#define LOG2E 1.44269504088896f

// round-to-nearest-even fp32 -> bf16
static __device__ __forceinline__ u16 f2bf(float f) {
    union { float f; u32 u; } v; v.f = f;
    u32 u = v.u;
    return (u16)((u + 0x7FFFu + ((u >> 16) & 1u)) >> 16);
}

static __device__ __forceinline__ u32 cvtpk(float a, float b) {
    u32 r;
    asm("v_cvt_pk_bf16_f32 %0, %1, %2" : "=v"(r) : "v"(a), "v"(b));
    return r;
}

static __device__ __forceinline__ float vexp2(float x) {
    float r;
    asm("v_exp_f32 %0, %1" : "=v"(r) : "v"(x));
    return r;
}

// exchange: a' = [a.lo32 | b.lo32(partner)], b' = [a.hi32(partner) | b.hi32]
static __device__ __forceinline__ void plswap(u32& a, u32& b) {
#if __has_builtin(__builtin_amdgcn_permlane32_swap)
    u32x2 r = __builtin_amdgcn_permlane32_swap(a, b, false, false);
    a = r[0]; b = r[1];
#else
    u32 sa = __shfl_xor(a, 32), sb = __shfl_xor(b, 32);
    bool hi = (threadIdx.x & 32) != 0;
    u32 na = hi ? sb : a;
    u32 nb = hi ? b : sa;
    a = na; b = nb;
#endif
}

// ---------------------------------------------------------------------------
// Weight prep: wt[mat][n][k] = bf16(w[mat][k][n]), mat: q,k,v,o
__global__ void __launch_bounds__(256) k_prep(const float* __restrict__ wq,
        const float* __restrict__ wk, const float* __restrict__ wv,
        const float* __restrict__ wo, u16* __restrict__ wt) {
    int i = blockIdx.x * 256 + threadIdx.x;
    int mat = i >> 14, rem = i & 16383;
    int k = rem >> 7, n = rem & 127;
    const float* src = mat == 0 ? wq : mat == 1 ? wk : mat == 2 ? wv : wo;
    wt[mat * 16384 + n * 128 + k] = f2bf(src[rem]);
}

// ---------------------------------------------------------------------------
// Fully fused: LN -> QKV (LDS) -> attention -> out-proj. One block per seq
// row (256 blocks = 256 CUs), 512 threads = 8 waves = 8 heads.
// r12 structure; deltas (both r11-hardware-proven): PV o0/o1 split + cvtpk
// ctx epilogue. NOTE: va[8] hoist and forced qt unroll are on the forbidden
// list (r13 NaN, mechanism unexplained); phase-3 loads stay in-loop.
// LDS map (132 KB):
//   [0,      34816)  Xs   : LN'd X, [128 tok][136 u16]  (reused as ctxs)
//   [34816,  67584)  Qs   : [8 h][128 tok][16 d] u16, XOR-swz idx^((tok&4)<<1)
//   [67584, 100352)  Ks   : same as Qs
//   [100352,135168)  Vs   : [8 h][16 d][136 tok-pitch] u16
__global__ void __launch_bounds__(512) k_fused(const float* __restrict__ pe,
        const float* __restrict__ g, const float* __restrict__ bia,
        const u16* __restrict__ wt,
        const float* __restrict__ bq, const float* __restrict__ bk,
        const float* __restrict__ bv, const float* __restrict__ bo,
        const float* __restrict__ mask, float* __restrict__ out) {
    __shared__ __align__(16) char smem[135168];
    u16* Xs = reinterpret_cast<u16*>(smem);            // pitch 136
    u16* Qs = reinterpret_cast<u16*>(smem + 34816);
    u16* Ks = reinterpret_cast<u16*>(smem + 67584);
    u16* Vs = reinterpret_cast<u16*>(smem + 100352);
    char* ctxs = smem;                                  // 256B-pitch, swizzled

    int tid = threadIdx.x;
    int seq = blockIdx.x;
    int lane = tid & 63, h = tid >> 6;
    int lo = lane & 15, hi = lane >> 4;

    // ---- W fragments + biases preloaded before LN (L2 latency hides) ----
    bf16x8 bf[3][4];
#pragma unroll
    for (int mat = 0; mat < 3; ++mat)
#pragma unroll
        for (int kk = 0; kk < 4; ++kk)
            bf[mat][kk] = *reinterpret_cast<const bf16x8*>(
                wt + mat * 16384 + (h * 16 + lo) * 128 + kk * 32 + hi * 8);
    float4 bq4 = *reinterpret_cast<const float4*>(bq + h * 16 + hi * 4);
    float4 bk4 = *reinterpret_cast<const float4*>(bk + h * 16 + hi * 4);
    float bv_ = bv[h * 16 + lo];

    // ---- Phase 1: LayerNorm, 4 threads/token, 128 tokens ----
    {
        int tl = tid >> 2;
        int q = tid & 3;
        const float4* src = reinterpret_cast<const float4*>(pe + (size_t)(seq * 128 + tl) * EMB);
        float4 v[8];
        float s = 0.f, ss = 0.f;
#pragma unroll
        for (int i = 0; i < 8; ++i) {
            v[i] = src[i * 4 + q];
            s += v[i].x + v[i].y + v[i].z + v[i].w;
            ss += v[i].x * v[i].x + v[i].y * v[i].y + v[i].z * v[i].z + v[i].w * v[i].w;
        }
        s += __shfl_xor(s, 1); ss += __shfl_xor(ss, 1);
        s += __shfl_xor(s, 2); ss += __shfl_xor(ss, 2);
        float mean = s * (1.f / EMB);
        float var = ss * (1.f / EMB) - mean * mean;
        float rstd = rsqrtf(var + 1e-5f);
#pragma unroll
        for (int i = 0; i < 8; ++i) {
            int c = i * 16 + q * 4;
            float4 gg = *reinterpret_cast<const float4*>(g + c);
            float4 bb = *reinterpret_cast<const float4*>(bia + c);
            uint2 packed;
            packed.x = (u32)f2bf((v[i].x - mean) * rstd * gg.x + bb.x)
                     | ((u32)f2bf((v[i].y - mean) * rstd * gg.y + bb.y) << 16);
            packed.y = (u32)f2bf((v[i].z - mean) * rstd * gg.z + bb.z)
                     | ((u32)f2bf((v[i].w - mean) * rstd * gg.w + bb.w) << 16);
            *reinterpret_cast<uint2*>(&Xs[tl * 136 + c]) = packed;
        }
    }
    __syncthreads();

    // ---- Phase 2: per-head QKV GEMM (W in regs) -> LDS ----
    {
#pragma unroll
        for (int sub = 0; sub < 8; ++sub) {
            bf16x8 a[4];
#pragma unroll
            for (int kk = 0; kk < 4; ++kk)
                a[kk] = *reinterpret_cast<const bf16x8*>(&Xs[(sub * 16 + lo) * 136 + kk * 32 + hi * 8]);
            f32x4 aq = {}, ak = {}, av = {};
#pragma unroll
            for (int kk = 0; kk < 4; ++kk) {
                // swapped: D col = token = lo, row = d = hi*4+j
                aq = __builtin_amdgcn_mfma_f32_16x16x32_bf16(bf[0][kk], a[kk], aq, 0, 0, 0);
                ak = __builtin_amdgcn_mfma_f32_16x16x32_bf16(bf[1][kk], a[kk], ak, 0, 0, 0);
                // normal: D col = d = lo, row = token = hi*4+j
                av = __builtin_amdgcn_mfma_f32_16x16x32_bf16(a[kk], bf[2][kk], av, 0, 0, 0);
            }
            // Q/K packed write: token = sub*16+lo, d = hi*4..hi*4+3
            {
                int tok = sub * 16 + lo;
                int idx = ((h << 11) + tok * 16 + hi * 4) ^ ((tok & 4) << 1);
                uint2 pq, pk;
                pq.x = (u32)f2bf((aq[0] + bq4.x) * 0.25f) | ((u32)f2bf((aq[1] + bq4.y) * 0.25f) << 16);
                pq.y = (u32)f2bf((aq[2] + bq4.z) * 0.25f) | ((u32)f2bf((aq[3] + bq4.w) * 0.25f) << 16);
                pk.x = (u32)f2bf(ak[0] + bk4.x) | ((u32)f2bf(ak[1] + bk4.y) << 16);
                pk.y = (u32)f2bf(ak[2] + bk4.z) | ((u32)f2bf(ak[3] + bk4.w) << 16);
                *reinterpret_cast<uint2*>(&Qs[idx]) = pq;
                *reinterpret_cast<uint2*>(&Ks[idx]) = pk;
            }
            // V packed write: [d=lo][tok], tok = sub*16 + hi*4 + j
            {
                int tokv = sub * 16 + hi * 4;
                uint2 pv;
                pv.x = (u32)f2bf(av[0] + bv_) | ((u32)f2bf(av[1] + bv_) << 16);
                pv.y = (u32)f2bf(av[2] + bv_) | ((u32)f2bf(av[3] + bv_) << 16);
                *reinterpret_cast<uint2*>(&Vs[h * 2176 + lo * 136 + tokv]) = pv;
            }
        }
    }
    __syncthreads();

    // ---- Phase 3: attention (reads Qs/Ks/Vs; writes ctxs = Xs region) ----
    {
        int lo2 = lane & 31, hi2 = lane >> 5;
        int swz = (lo2 & 4) << 1;            // tok&4 == lo2&4 for tok = t*32+lo2
        const f32x16 zero = {};

        bf16x8 kf[4];
#pragma unroll
        for (int t = 0; t < 4; ++t)
            kf[t] = *reinterpret_cast<const bf16x8*>(
                &Ks[(h << 11) + (((t * 32 + lo2) * 16 + hi2 * 8) ^ swz)]);

        for (int qt = 0; qt < 4; ++qt) {
            bf16x8 qf = *reinterpret_cast<const bf16x8*>(
                &Qs[(h << 11) + (((qt * 32 + lo2) * 16 + hi2 * 8) ^ swz)]);
            f32x16 s[4];
#pragma unroll
            for (int t = 0; t < 4; ++t)
                s[t] = __builtin_amdgcn_mfma_f32_32x32x16_bf16(kf[t], qf, zero, 0, 0, 0);

            // tree max (depth ~6) instead of 63-deep serial chain
            float mA[16];
#pragma unroll
            for (int i = 0; i < 16; ++i)
                mA[i] = fmaxf(fmaxf(s[0][i], s[1][i]), fmaxf(s[2][i], s[3][i]));
#pragma unroll
            for (int i = 0; i < 8; ++i) mA[i] = fmaxf(mA[i], mA[i + 8]);
#pragma unroll
            for (int i = 0; i < 4; ++i) mA[i] = fmaxf(mA[i], mA[i + 4]);
            float m = fmaxf(fmaxf(mA[0], mA[1]), fmaxf(mA[2], mA[3]));
            m = fmaxf(m, __shfl_xor(m, 32));
            float m2 = m * LOG2E;

            // exp(s-m) = 2^(s*log2e - m2): one FMA + one v_exp per element
            float sm0 = 0.f, sm1 = 0.f, sm2 = 0.f, sm3 = 0.f;
#pragma unroll
            for (int t = 0; t < 4; ++t)
#pragma unroll
                for (int r = 0; r < 16; ++r) {
                    float p = vexp2(__builtin_fmaf(s[t][r], LOG2E, -m2));
                    s[t][r] = p;
                    if (t == 0) sm0 += p; else if (t == 1) sm1 += p;
                    else if (t == 2) sm2 += p; else sm3 += p;
                }
            float sum = (sm0 + sm1) + (sm2 + sm3);
            sum += __shfl_xor(sum, 32);
            float inv = 1.f / sum;

            // P -> bf16 frags; PV with two independent accumulator chains
            // (va loads stay in-loop: hoisting them was r13's NaN trigger)
            f32x16 o0 = {}, o1 = {};
#pragma unroll
            for (int c = 0; c < 8; ++c) {
                int t = c >> 1, hf = (c & 1) * 8;
                u32 x0 = cvtpk(s[t][hf + 0], s[t][hf + 1]);
                u32 x1 = cvtpk(s[t][hf + 2], s[t][hf + 3]);
                u32 y0 = cvtpk(s[t][hf + 4], s[t][hf + 5]);
                u32 y1 = cvtpk(s[t][hf + 6], s[t][hf + 7]);
                plswap(x0, y0);
                plswap(x1, y1);
                union { u32 wd[4]; bf16x8 v; } pb;
                pb.wd[0] = x0; pb.wd[1] = x1; pb.wd[2] = y0; pb.wd[3] = y1;
                bf16x8 va = *reinterpret_cast<const bf16x8*>(
                    &Vs[h * 2176 + (lo2 & 15) * 136 + c * 16 + hi2 * 8]);
                if (c & 1)
                    o1 = __builtin_amdgcn_mfma_f32_32x32x16_bf16(va, pb.v, o1, 0, 0, 0);
                else
                    o0 = __builtin_amdgcn_mfma_f32_32x32x16_bf16(va, pb.v, o0, 0, 0, 0);
            }

            int tok = qt * 32 + lo2;
            u32 off0 = (u32)(tok * 256 + h * 32 + 8 * hi2) ^ ((tok & 7) << 4);
            u32 off1 = (u32)(tok * 256 + h * 32 + 16 + 8 * hi2) ^ ((tok & 7) << 4);
            uint2 p0, p1;
            p0.x = cvtpk((o0[0] + o1[0]) * inv, (o0[1] + o1[1]) * inv);
            p0.y = cvtpk((o0[2] + o1[2]) * inv, (o0[3] + o1[3]) * inv);
            p1.x = cvtpk((o0[4] + o1[4]) * inv, (o0[5] + o1[5]) * inv);
            p1.y = cvtpk((o0[6] + o1[6]) * inv, (o0[7] + o1[7]) * inv);
            *reinterpret_cast<uint2*>(ctxs + off0) = p0;
            *reinterpret_cast<uint2*>(ctxs + off1) = p1;
        }
    }
    __syncthreads();

    // ---- Phase 4: out-proj; wave h does tokens [h*16, h*16+16) ----
    {
        const u16* wo = wt + 3 * 16384;
        f32x4 acc[8];
#pragma unroll
        for (int c = 0; c < 8; ++c) acc[c] = f32x4{0.f, 0.f, 0.f, 0.f};
#pragma unroll
        for (int kk = 0; kk < 4; ++kk) {
            int tokrow = h * 16 + lo;
            u32 aoff = (u32)(tokrow * 256 + kk * 64 + hi * 16) ^ ((tokrow & 7) << 4);
            bf16x8 a = *reinterpret_cast<const bf16x8*>(ctxs + aoff);
#pragma unroll
            for (int c = 0; c < 8; ++c) {
                bf16x8 b = *reinterpret_cast<const bf16x8*>(wo + (c * 16 + lo) * 128 + kk * 32 + hi * 8);
                acc[c] = __builtin_amdgcn_mfma_f32_16x16x32_bf16(a, b, acc[c], 0, 0, 0);
            }
        }
#pragma unroll
        for (int c = 0; c < 8; ++c) {
            int col = c * 16 + lo;
            float bval = bo[col];
#pragma unroll
            for (int j = 0; j < 4; ++j) {
                int t = seq * 128 + h * 16 + hi * 4 + j;
                out[(size_t)t * EMB + col] = (acc[c][j] + bval) * mask[t];
            }
        }
    }
}

// ---------------------------------------------------------------------------
extern "C" void kernel_launch(void* const* d_in, const int* in_sizes, int n_in,
                              void* d_out, int out_size, void* d_ws, size_t ws_size,
                              hipStream_t stream) {
    const float* pe   = (const float*)d_in[0];
    const float* mask = (const float*)d_in[1];
    const float* ln_g = (const float*)d_in[2];
    const float* ln_b = (const float*)d_in[3];
    const float* wq   = (const float*)d_in[4];
    const float* bq   = (const float*)d_in[5];
    const float* wk   = (const float*)d_in[6];
    const float* bk   = (const float*)d_in[7];
    const float* wv   = (const float*)d_in[8];
    const float* bv   = (const float*)d_in[9];
    const float* wo   = (const float*)d_in[10];
    const float* bo   = (const float*)d_in[11];
    float* out = (float*)d_out;

    u16* wt = (u16*)d_ws;            // 4 x [n][k] bf16 = 128 KB

    hipLaunchKernelGGL(k_prep,  dim3(256), dim3(256), 0, stream, wq, wk, wv, wo, wt);
    hipLaunchKernelGGL(k_fused, dim3(256), dim3(512), 0, stream, pe, ln_g, ln_b, wt,
                       bq, bk, bv, bo, mask, out);
}

// Round 16
// 28.016 us; speedup vs baseline: 1.5324x; 1.2728x over previous
//
#include <hip/hip_runtime.h>
#include <hip/hip_bf16.h>

typedef __attribute__((ext_vector_type(8))) short bf16x8;
typedef __attribute__((ext_vector_type(4))) float f32x4;
typedef __attribute__((ext_vector_type(16))) float f32x16;
typedef __attribute__((ext_vector_type(2))) unsigned int u32x2;
typedef unsigned short u16;
typedef unsigned int u32;

#define EMB 128
#define LOG2E 1.44269504088896f

// round-to-nearest-even fp32 -> bf16
static __device__ __forceinline__ u16 f2bf(float f) {
    union { float f; u32 u; } v; v.f = f;
    u32 u = v.u;
    return (u16)((u + 0x7FFFu + ((u >> 16) & 1u)) >> 16);
}

static __device__ __forceinline__ u32 cvtpk(float a, float b) {
    u32 r;
    asm("v_cvt_pk_bf16_f32 %0, %1, %2" : "=v"(r) : "v"(a), "v"(b));
    return r;
}

static __device__ __forceinline__ float vexp2(float x) {
    float r;
    asm("v_exp_f32 %0, %1" : "=v"(r) : "v"(x));
    return r;
}

// exchange: a' = [a.lo32 | b.lo32(partner)], b' = [a.hi32(partner) | b.hi32]
static __device__ __forceinline__ void plswap(u32& a, u32& b) {
#if __has_builtin(__builtin_amdgcn_permlane32_swap)
    u32x2 r = __builtin_amdgcn_permlane32_swap(a, b, false, false);
    a = r[0]; b = r[1];
#else
    u32 sa = __shfl_xor(a, 32), sb = __shfl_xor(b, 32);
    bool hi = (threadIdx.x & 32) != 0;
    u32 na = hi ? sb : a;
    u32 nb = hi ? b : sa;
    a = na; b = nb;
#endif
}

// ---------------------------------------------------------------------------
// Single fully fused kernel: weights converted in-kernel (no k_prep launch).
// One block per seq row (256 blocks), 512 threads = 8 waves = 8 heads.
// Phases 1-3 are byte-identical to the green r14 kernel. New: QKV W preload
// gathers fp32 directly (values identical, RTNE); phase 3.5 converts Wo
// fp32 -> bf16 into the dead Ks LDS region (ctx-proven swizzle); phase 4
// reads its B fragments from LDS instead of global.
// LDS map (132 KB):
//   [0,      34816)  Xs   : LN'd X, [128 tok][136 u16]  (reused as ctxs)
//   [34816,  67584)  Qs   : [8 h][128 tok][16 d] u16, XOR-swz idx^((tok&4)<<1)
//   [67584, 100352)  Ks   : same as Qs (reused as swizzled Wo after phase 3)
//   [100352,135168)  Vs   : [8 h][16 d][136 tok-pitch] u16
__global__ void __launch_bounds__(512) k_fused(const float* __restrict__ pe,
        const float* __restrict__ g, const float* __restrict__ bia,
        const float* __restrict__ wq_f, const float* __restrict__ wk_f,
        const float* __restrict__ wv_f, const float* __restrict__ wo_f,
        const float* __restrict__ bq, const float* __restrict__ bk,
        const float* __restrict__ bv, const float* __restrict__ bo,
        const float* __restrict__ mask, float* __restrict__ out) {
    __shared__ __align__(16) char smem[135168];
    u16* Xs = reinterpret_cast<u16*>(smem);            // pitch 136
    u16* Qs = reinterpret_cast<u16*>(smem + 34816);
    u16* Ks = reinterpret_cast<u16*>(smem + 67584);
    u16* Vs = reinterpret_cast<u16*>(smem + 100352);
    char* ctxs = smem;                                  // 256B-pitch, swizzled
    char* wob = smem + 67584;                           // Wo bf16, 256B-pitch, swizzled

    int tid = threadIdx.x;
    int seq = blockIdx.x;
    int lane = tid & 63, h = tid >> 6;
    int lo = lane & 15, hi = lane >> 4;

    // ---- W fragments + biases: gather fp32 directly, pack with cvtpk.
    // Element e of bf[mat][kk] = w_mat[k = kk*32+hi*8+e][n = h*16+lo]
    // (identical values to the old k_prep path; both RTNE).
    bf16x8 bf[3][4];
    {
        const float* wsrc0 = wq_f + h * 16 + lo;
        const float* wsrc1 = wk_f + h * 16 + lo;
        const float* wsrc2 = wv_f + h * 16 + lo;
#pragma unroll
        for (int mat = 0; mat < 3; ++mat) {
            const float* ws = mat == 0 ? wsrc0 : mat == 1 ? wsrc1 : wsrc2;
#pragma unroll
            for (int kk = 0; kk < 4; ++kk) {
                const float* base = ws + (kk * 32 + hi * 8) * 128;
                union { u32 w[4]; bf16x8 v; } u;
                u.w[0] = cvtpk(base[0],   base[128]);
                u.w[1] = cvtpk(base[256], base[384]);
                u.w[2] = cvtpk(base[512], base[640]);
                u.w[3] = cvtpk(base[768], base[896]);
                bf[mat][kk] = u.v;
            }
        }
    }
    float4 bq4 = *reinterpret_cast<const float4*>(bq + h * 16 + hi * 4);
    float4 bk4 = *reinterpret_cast<const float4*>(bk + h * 16 + hi * 4);
    float bv_ = bv[h * 16 + lo];

    // ---- Phase 1: LayerNorm, 4 threads/token, 128 tokens (r14 verbatim) ----
    {
        int tl = tid >> 2;
        int q = tid & 3;
        const float4* src = reinterpret_cast<const float4*>(pe + (size_t)(seq * 128 + tl) * EMB);
        float4 v[8];
        float s = 0.f, ss = 0.f;
#pragma unroll
        for (int i = 0; i < 8; ++i) {
            v[i] = src[i * 4 + q];
            s += v[i].x + v[i].y + v[i].z + v[i].w;
            ss += v[i].x * v[i].x + v[i].y * v[i].y + v[i].z * v[i].z + v[i].w * v[i].w;
        }
        s += __shfl_xor(s, 1); ss += __shfl_xor(ss, 1);
        s += __shfl_xor(s, 2); ss += __shfl_xor(ss, 2);
        float mean = s * (1.f / EMB);
        float var = ss * (1.f / EMB) - mean * mean;
        float rstd = rsqrtf(var + 1e-5f);
#pragma unroll
        for (int i = 0; i < 8; ++i) {
            int c = i * 16 + q * 4;
            float4 gg = *reinterpret_cast<const float4*>(g + c);
            float4 bb = *reinterpret_cast<const float4*>(bia + c);
            uint2 packed;
            packed.x = (u32)f2bf((v[i].x - mean) * rstd * gg.x + bb.x)
                     | ((u32)f2bf((v[i].y - mean) * rstd * gg.y + bb.y) << 16);
            packed.y = (u32)f2bf((v[i].z - mean) * rstd * gg.z + bb.z)
                     | ((u32)f2bf((v[i].w - mean) * rstd * gg.w + bb.w) << 16);
            *reinterpret_cast<uint2*>(&Xs[tl * 136 + c]) = packed;
        }
    }
    __syncthreads();

    // ---- Phase 2: per-head QKV GEMM (W in regs) -> LDS (r14 verbatim) ----
    {
#pragma unroll
        for (int sub = 0; sub < 8; ++sub) {
            bf16x8 a[4];
#pragma unroll
            for (int kk = 0; kk < 4; ++kk)
                a[kk] = *reinterpret_cast<const bf16x8*>(&Xs[(sub * 16 + lo) * 136 + kk * 32 + hi * 8]);
            f32x4 aq = {}, ak = {}, av = {};
#pragma unroll
            for (int kk = 0; kk < 4; ++kk) {
                // swapped: D col = token = lo, row = d = hi*4+j
                aq = __builtin_amdgcn_mfma_f32_16x16x32_bf16(bf[0][kk], a[kk], aq, 0, 0, 0);
                ak = __builtin_amdgcn_mfma_f32_16x16x32_bf16(bf[1][kk], a[kk], ak, 0, 0, 0);
                // normal: D col = d = lo, row = token = hi*4+j
                av = __builtin_amdgcn_mfma_f32_16x16x32_bf16(a[kk], bf[2][kk], av, 0, 0, 0);
            }
            // Q/K packed write: token = sub*16+lo, d = hi*4..hi*4+3
            {
                int tok = sub * 16 + lo;
                int idx = ((h << 11) + tok * 16 + hi * 4) ^ ((tok & 4) << 1);
                uint2 pq, pk;
                pq.x = (u32)f2bf((aq[0] + bq4.x) * 0.25f) | ((u32)f2bf((aq[1] + bq4.y) * 0.25f) << 16);
                pq.y = (u32)f2bf((aq[2] + bq4.z) * 0.25f) | ((u32)f2bf((aq[3] + bq4.w) * 0.25f) << 16);
                pk.x = (u32)f2bf(ak[0] + bk4.x) | ((u32)f2bf(ak[1] + bk4.y) << 16);
                pk.y = (u32)f2bf(ak[2] + bk4.z) | ((u32)f2bf(ak[3] + bk4.w) << 16);
                *reinterpret_cast<uint2*>(&Qs[idx]) = pq;
                *reinterpret_cast<uint2*>(&Ks[idx]) = pk;
            }
            // V packed write: [d=lo][tok], tok = sub*16 + hi*4 + j
            {
                int tokv = sub * 16 + hi * 4;
                uint2 pv;
                pv.x = (u32)f2bf(av[0] + bv_) | ((u32)f2bf(av[1] + bv_) << 16);
                pv.y = (u32)f2bf(av[2] + bv_) | ((u32)f2bf(av[3] + bv_) << 16);
                *reinterpret_cast<uint2*>(&Vs[h * 2176 + lo * 136 + tokv]) = pv;
            }
        }
    }
    __syncthreads();

    // ---- Phase 3: attention (r14 verbatim) ----
    {
        int lo2 = lane & 31, hi2 = lane >> 5;
        int swz = (lo2 & 4) << 1;            // tok&4 == lo2&4 for tok = t*32+lo2
        const f32x16 zero = {};

        bf16x8 kf[4];
#pragma unroll
        for (int t = 0; t < 4; ++t)
            kf[t] = *reinterpret_cast<const bf16x8*>(
                &Ks[(h << 11) + (((t * 32 + lo2) * 16 + hi2 * 8) ^ swz)]);

        for (int qt = 0; qt < 4; ++qt) {
            bf16x8 qf = *reinterpret_cast<const bf16x8*>(
                &Qs[(h << 11) + (((qt * 32 + lo2) * 16 + hi2 * 8) ^ swz)]);
            f32x16 s[4];
#pragma unroll
            for (int t = 0; t < 4; ++t)
                s[t] = __builtin_amdgcn_mfma_f32_32x32x16_bf16(kf[t], qf, zero, 0, 0, 0);

            // tree max (depth ~6)
            float mA[16];
#pragma unroll
            for (int i = 0; i < 16; ++i)
                mA[i] = fmaxf(fmaxf(s[0][i], s[1][i]), fmaxf(s[2][i], s[3][i]));
#pragma unroll
            for (int i = 0; i < 8; ++i) mA[i] = fmaxf(mA[i], mA[i + 8]);
#pragma unroll
            for (int i = 0; i < 4; ++i) mA[i] = fmaxf(mA[i], mA[i + 4]);
            float m = fmaxf(fmaxf(mA[0], mA[1]), fmaxf(mA[2], mA[3]));
            m = fmaxf(m, __shfl_xor(m, 32));
            float m2 = m * LOG2E;

            float sm0 = 0.f, sm1 = 0.f, sm2 = 0.f, sm3 = 0.f;
#pragma unroll
            for (int t = 0; t < 4; ++t)
#pragma unroll
                for (int r = 0; r < 16; ++r) {
                    float p = vexp2(__builtin_fmaf(s[t][r], LOG2E, -m2));
                    s[t][r] = p;
                    if (t == 0) sm0 += p; else if (t == 1) sm1 += p;
                    else if (t == 2) sm2 += p; else sm3 += p;
                }
            float sum = (sm0 + sm1) + (sm2 + sm3);
            sum += __shfl_xor(sum, 32);
            float inv = 1.f / sum;

            f32x16 o0 = {}, o1 = {};
#pragma unroll
            for (int c = 0; c < 8; ++c) {
                int t = c >> 1, hf = (c & 1) * 8;
                u32 x0 = cvtpk(s[t][hf + 0], s[t][hf + 1]);
                u32 x1 = cvtpk(s[t][hf + 2], s[t][hf + 3]);
                u32 y0 = cvtpk(s[t][hf + 4], s[t][hf + 5]);
                u32 y1 = cvtpk(s[t][hf + 6], s[t][hf + 7]);
                plswap(x0, y0);
                plswap(x1, y1);
                union { u32 wd[4]; bf16x8 v; } pb;
                pb.wd[0] = x0; pb.wd[1] = x1; pb.wd[2] = y0; pb.wd[3] = y1;
                bf16x8 va = *reinterpret_cast<const bf16x8*>(
                    &Vs[h * 2176 + (lo2 & 15) * 136 + c * 16 + hi2 * 8]);
                if (c & 1)
                    o1 = __builtin_amdgcn_mfma_f32_32x32x16_bf16(va, pb.v, o1, 0, 0, 0);
                else
                    o0 = __builtin_amdgcn_mfma_f32_32x32x16_bf16(va, pb.v, o0, 0, 0, 0);
            }

            int tok = qt * 32 + lo2;
            u32 off0 = (u32)(tok * 256 + h * 32 + 8 * hi2) ^ ((tok & 7) << 4);
            u32 off1 = (u32)(tok * 256 + h * 32 + 16 + 8 * hi2) ^ ((tok & 7) << 4);
            uint2 p0, p1;
            p0.x = cvtpk((o0[0] + o1[0]) * inv, (o0[1] + o1[1]) * inv);
            p0.y = cvtpk((o0[2] + o1[2]) * inv, (o0[3] + o1[3]) * inv);
            p1.x = cvtpk((o0[4] + o1[4]) * inv, (o0[5] + o1[5]) * inv);
            p1.y = cvtpk((o0[6] + o1[6]) * inv, (o0[7] + o1[7]) * inv);
            *reinterpret_cast<uint2*>(ctxs + off0) = p0;
            *reinterpret_cast<uint2*>(ctxs + off1) = p1;
        }
    }
    __syncthreads();   // all phase-3 reads of Qs/Ks/Vs complete; ctx ready

    // ---- Phase 3.5: Wo fp32 -> bf16 into dead Ks region (swizzled rows).
    // Value v = wo_f[k][n] goes to row n, col k: byte = n*256 + k*2,
    // swizzled ^ ((n&7)<<4) — same formula family as the green ctxs layout.
#pragma unroll
    for (int i = 0; i < 8; ++i) {
        int idx4 = i * 512 + tid;          // 0..4095 float4s
        int k = idx4 >> 5;                 // 0..127
        int n0 = (idx4 & 31) * 4;          // 0..124, 4-aligned
        float4 v4 = *reinterpret_cast<const float4*>(wo_f + k * 128 + n0);
        *reinterpret_cast<u16*>(wob + ((u32)((n0 + 0) * 256 + k * 2) ^ (((n0 + 0) & 7) << 4))) = f2bf(v4.x);
        *reinterpret_cast<u16*>(wob + ((u32)((n0 + 1) * 256 + k * 2) ^ (((n0 + 1) & 7) << 4))) = f2bf(v4.y);
        *reinterpret_cast<u16*>(wob + ((u32)((n0 + 2) * 256 + k * 2) ^ (((n0 + 2) & 7) << 4))) = f2bf(v4.z);
        *reinterpret_cast<u16*>(wob + ((u32)((n0 + 3) * 256 + k * 2) ^ (((n0 + 3) & 7) << 4))) = f2bf(v4.w);
    }
    __syncthreads();   // wo_lds ready for all waves

    // ---- Phase 4: out-proj; wave h does tokens [h*16, h*16+16).
    // B fragments now from swizzled LDS (was: global L2). Row (c*16+lo) has
    // (row&7) == (lo&7), so the read swizzle is ^((lo&7)<<4).
    {
        f32x4 acc[8];
#pragma unroll
        for (int c = 0; c < 8; ++c) acc[c] = f32x4{0.f, 0.f, 0.f, 0.f};
#pragma unroll
        for (int kk = 0; kk < 4; ++kk) {
            int tokrow = h * 16 + lo;
            u32 aoff = (u32)(tokrow * 256 + kk * 64 + hi * 16) ^ ((tokrow & 7) << 4);
            bf16x8 a = *reinterpret_cast<const bf16x8*>(ctxs + aoff);
#pragma unroll
            for (int c = 0; c < 8; ++c) {
                u32 boff = (u32)((c * 16 + lo) * 256 + kk * 64 + hi * 16) ^ ((lo & 7) << 4);
                bf16x8 b = *reinterpret_cast<const bf16x8*>(wob + boff);
                acc[c] = __builtin_amdgcn_mfma_f32_16x16x32_bf16(a, b, acc[c], 0, 0, 0);
            }
        }
#pragma unroll
        for (int c = 0; c < 8; ++c) {
            int col = c * 16 + lo;
            float bval = bo[col];
#pragma unroll
            for (int j = 0; j < 4; ++j) {
                int t = seq * 128 + h * 16 + hi * 4 + j;
                out[(size_t)t * EMB + col] = (acc[c][j] + bval) * mask[t];
            }
        }
    }
}

// ---------------------------------------------------------------------------
extern "C" void kernel_launch(void* const* d_in, const int* in_sizes, int n_in,
                              void* d_out, int out_size, void* d_ws, size_t ws_size,
                              hipStream_t stream) {
    const float* pe   = (const float*)d_in[0];
    const float* mask = (const float*)d_in[1];
    const float* ln_g = (const float*)d_in[2];
    const float* ln_b = (const float*)d_in[3];
    const float* wq   = (const float*)d_in[4];
    const float* bq   = (const float*)d_in[5];
    const float* wk   = (const float*)d_in[6];
    const float* bk   = (const float*)d_in[7];
    const float* wv   = (const float*)d_in[8];
    const float* bv   = (const float*)d_in[9];
    const float* wo   = (const float*)d_in[10];
    const float* bo   = (const float*)d_in[11];
    float* out = (float*)d_out;

    hipLaunchKernelGGL(k_fused, dim3(256), dim3(512), 0, stream, pe, ln_g, ln_b,
                       wq, wk, wv, wo, bq, bk, bv, bo, mask, out);
}

// Round 17
// 25.210 us; speedup vs baseline: 1.7030x; 1.1113x over previous
//
#include <hip/hip_runtime.h>
#include <hip/hip_bf16.h>

typedef __attribute__((ext_vector_type(8))) short bf16x8;
typedef __attribute__((ext_vector_type(4))) float f32x4;
typedef __attribute__((ext_vector_type(16))) float f32x16;
typedef __attribute__((ext_vector_type(2))) unsigned int u32x2;
typedef unsigned short u16;
typedef unsigned int u32;

#define EMB 128
#define LOG2E 1.44269504088896f

// round-to-nearest-even fp32 -> bf16
static __device__ __forceinline__ u16 f2bf(float f) {
    union { float f; u32 u; } v; v.f = f;
    u32 u = v.u;
    return (u16)((u + 0x7FFFu + ((u >> 16) & 1u)) >> 16);
}

static __device__ __forceinline__ u32 cvtpk(float a, float b) {
    u32 r;
    asm("v_cvt_pk_bf16_f32 %0, %1, %2" : "=v"(r) : "v"(a), "v"(b));
    return r;
}

static __device__ __forceinline__ float vexp2(float x) {
    float r;
    asm("v_exp_f32 %0, %1" : "=v"(r) : "v"(x));
    return r;
}

// exchange: a' = [a.lo32 | b.lo32(partner)], b' = [a.hi32(partner) | b.hi32]
static __device__ __forceinline__ void plswap(u32& a, u32& b) {
#if __has_builtin(__builtin_amdgcn_permlane32_swap)
    u32x2 r = __builtin_amdgcn_permlane32_swap(a, b, false, false);
    a = r[0]; b = r[1];
#else
    u32 sa = __shfl_xor(a, 32), sb = __shfl_xor(b, 32);
    bool hi = (threadIdx.x & 32) != 0;
    u32 na = hi ? sb : a;
    u32 nb = hi ? b : sa;
    a = na; b = nb;
#endif
}

// ---------------------------------------------------------------------------
// Single fully fused kernel (r16-green base). Deltas this round (value-level
// only): Wo prefetched to registers before LN; phase 3.5 uses transposed
// ownership (thread owns n, k0..k0+3) -> one packed 8B store instead of 4
// scalar u16 stores (16-way -> ~8-way conflicts, 4x fewer stores).
// LDS map (132 KB):
//   [0,      34816)  Xs   : LN'd X, [128 tok][136 u16]  (reused as ctxs)
//   [34816,  67584)  Qs   : [8 h][128 tok][16 d] u16, XOR-swz idx^((tok&4)<<1)
//   [67584, 100352)  Ks   : same as Qs (reused as swizzled Wo after phase 3)
//   [100352,135168)  Vs   : [8 h][16 d][136 tok-pitch] u16
__global__ void __launch_bounds__(512) k_fused(const float* __restrict__ pe,
        const float* __restrict__ g, const float* __restrict__ bia,
        const float* __restrict__ wq_f, const float* __restrict__ wk_f,
        const float* __restrict__ wv_f, const float* __restrict__ wo_f,
        const float* __restrict__ bq, const float* __restrict__ bk,
        const float* __restrict__ bv, const float* __restrict__ bo,
        const float* __restrict__ mask, float* __restrict__ out) {
    __shared__ __align__(16) char smem[135168];
    u16* Xs = reinterpret_cast<u16*>(smem);            // pitch 136
    u16* Qs = reinterpret_cast<u16*>(smem + 34816);
    u16* Ks = reinterpret_cast<u16*>(smem + 67584);
    u16* Vs = reinterpret_cast<u16*>(smem + 100352);
    char* ctxs = smem;                                  // 256B-pitch, swizzled
    char* wob = smem + 67584;                           // Wo bf16, 256B-pitch, swizzled

    int tid = threadIdx.x;
    int seq = blockIdx.x;
    int lane = tid & 63, h = tid >> 6;
    int lo = lane & 15, hi = lane >> 4;

    // ---- QKV W fragments: gather fp32 directly, pack with cvtpk (r16) ----
    bf16x8 bf[3][4];
    {
        const float* wsrc0 = wq_f + h * 16 + lo;
        const float* wsrc1 = wk_f + h * 16 + lo;
        const float* wsrc2 = wv_f + h * 16 + lo;
#pragma unroll
        for (int mat = 0; mat < 3; ++mat) {
            const float* ws = mat == 0 ? wsrc0 : mat == 1 ? wsrc1 : wsrc2;
#pragma unroll
            for (int kk = 0; kk < 4; ++kk) {
                const float* base = ws + (kk * 32 + hi * 8) * 128;
                union { u32 w[4]; bf16x8 v; } u;
                u.w[0] = cvtpk(base[0],   base[128]);
                u.w[1] = cvtpk(base[256], base[384]);
                u.w[2] = cvtpk(base[512], base[640]);
                u.w[3] = cvtpk(base[768], base[896]);
                bf[mat][kk] = u.v;
            }
        }
    }
    float4 bq4 = *reinterpret_cast<const float4*>(bq + h * 16 + hi * 4);
    float4 bk4 = *reinterpret_cast<const float4*>(bk + h * 16 + hi * 4);
    float bv_ = bv[h * 16 + lo];

    // ---- Wo prefetch (transposed ownership: thread i owns (n, k0..k0+3)).
    // For fixed i,j lanes read consecutive n -> fully coalesced.
    float wpre[8][4];
#pragma unroll
    for (int i = 0; i < 8; ++i) {
        int idx = i * 512 + tid;        // 0..4095
        int n = idx & 127;
        int k0 = (idx >> 7) * 4;
#pragma unroll
        for (int j = 0; j < 4; ++j)
            wpre[i][j] = wo_f[(k0 + j) * 128 + n];
    }

    // ---- Phase 1: LayerNorm, 4 threads/token, 128 tokens (r14 verbatim) ----
    {
        int tl = tid >> 2;
        int q = tid & 3;
        const float4* src = reinterpret_cast<const float4*>(pe + (size_t)(seq * 128 + tl) * EMB);
        float4 v[8];
        float s = 0.f, ss = 0.f;
#pragma unroll
        for (int i = 0; i < 8; ++i) {
            v[i] = src[i * 4 + q];
            s += v[i].x + v[i].y + v[i].z + v[i].w;
            ss += v[i].x * v[i].x + v[i].y * v[i].y + v[i].z * v[i].z + v[i].w * v[i].w;
        }
        s += __shfl_xor(s, 1); ss += __shfl_xor(ss, 1);
        s += __shfl_xor(s, 2); ss += __shfl_xor(ss, 2);
        float mean = s * (1.f / EMB);
        float var = ss * (1.f / EMB) - mean * mean;
        float rstd = rsqrtf(var + 1e-5f);
#pragma unroll
        for (int i = 0; i < 8; ++i) {
            int c = i * 16 + q * 4;
            float4 gg = *reinterpret_cast<const float4*>(g + c);
            float4 bb = *reinterpret_cast<const float4*>(bia + c);
            uint2 packed;
            packed.x = (u32)f2bf((v[i].x - mean) * rstd * gg.x + bb.x)
                     | ((u32)f2bf((v[i].y - mean) * rstd * gg.y + bb.y) << 16);
            packed.y = (u32)f2bf((v[i].z - mean) * rstd * gg.z + bb.z)
                     | ((u32)f2bf((v[i].w - mean) * rstd * gg.w + bb.w) << 16);
            *reinterpret_cast<uint2*>(&Xs[tl * 136 + c]) = packed;
        }
    }
    __syncthreads();

    // ---- Phase 2: per-head QKV GEMM (W in regs) -> LDS (r14 verbatim) ----
    {
#pragma unroll
        for (int sub = 0; sub < 8; ++sub) {
            bf16x8 a[4];
#pragma unroll
            for (int kk = 0; kk < 4; ++kk)
                a[kk] = *reinterpret_cast<const bf16x8*>(&Xs[(sub * 16 + lo) * 136 + kk * 32 + hi * 8]);
            f32x4 aq = {}, ak = {}, av = {};
#pragma unroll
            for (int kk = 0; kk < 4; ++kk) {
                // swapped: D col = token = lo, row = d = hi*4+j
                aq = __builtin_amdgcn_mfma_f32_16x16x32_bf16(bf[0][kk], a[kk], aq, 0, 0, 0);
                ak = __builtin_amdgcn_mfma_f32_16x16x32_bf16(bf[1][kk], a[kk], ak, 0, 0, 0);
                // normal: D col = d = lo, row = token = hi*4+j
                av = __builtin_amdgcn_mfma_f32_16x16x32_bf16(a[kk], bf[2][kk], av, 0, 0, 0);
            }
            // Q/K packed write: token = sub*16+lo, d = hi*4..hi*4+3
            {
                int tok = sub * 16 + lo;
                int idx = ((h << 11) + tok * 16 + hi * 4) ^ ((tok & 4) << 1);
                uint2 pq, pk;
                pq.x = (u32)f2bf((aq[0] + bq4.x) * 0.25f) | ((u32)f2bf((aq[1] + bq4.y) * 0.25f) << 16);
                pq.y = (u32)f2bf((aq[2] + bq4.z) * 0.25f) | ((u32)f2bf((aq[3] + bq4.w) * 0.25f) << 16);
                pk.x = (u32)f2bf(ak[0] + bk4.x) | ((u32)f2bf(ak[1] + bk4.y) << 16);
                pk.y = (u32)f2bf(ak[2] + bk4.z) | ((u32)f2bf(ak[3] + bk4.w) << 16);
                *reinterpret_cast<uint2*>(&Qs[idx]) = pq;
                *reinterpret_cast<uint2*>(&Ks[idx]) = pk;
            }
            // V packed write: [d=lo][tok], tok = sub*16 + hi*4 + j
            {
                int tokv = sub * 16 + hi * 4;
                uint2 pv;
                pv.x = (u32)f2bf(av[0] + bv_) | ((u32)f2bf(av[1] + bv_) << 16);
                pv.y = (u32)f2bf(av[2] + bv_) | ((u32)f2bf(av[3] + bv_) << 16);
                *reinterpret_cast<uint2*>(&Vs[h * 2176 + lo * 136 + tokv]) = pv;
            }
        }
    }
    __syncthreads();

    // ---- Phase 3: attention (r14 verbatim) ----
    {
        int lo2 = lane & 31, hi2 = lane >> 5;
        int swz = (lo2 & 4) << 1;            // tok&4 == lo2&4 for tok = t*32+lo2
        const f32x16 zero = {};

        bf16x8 kf[4];
#pragma unroll
        for (int t = 0; t < 4; ++t)
            kf[t] = *reinterpret_cast<const bf16x8*>(
                &Ks[(h << 11) + (((t * 32 + lo2) * 16 + hi2 * 8) ^ swz)]);

        for (int qt = 0; qt < 4; ++qt) {
            bf16x8 qf = *reinterpret_cast<const bf16x8*>(
                &Qs[(h << 11) + (((qt * 32 + lo2) * 16 + hi2 * 8) ^ swz)]);
            f32x16 s[4];
#pragma unroll
            for (int t = 0; t < 4; ++t)
                s[t] = __builtin_amdgcn_mfma_f32_32x32x16_bf16(kf[t], qf, zero, 0, 0, 0);

            // tree max (depth ~6)
            float mA[16];
#pragma unroll
            for (int i = 0; i < 16; ++i)
                mA[i] = fmaxf(fmaxf(s[0][i], s[1][i]), fmaxf(s[2][i], s[3][i]));
#pragma unroll
            for (int i = 0; i < 8; ++i) mA[i] = fmaxf(mA[i], mA[i + 8]);
#pragma unroll
            for (int i = 0; i < 4; ++i) mA[i] = fmaxf(mA[i], mA[i + 4]);
            float m = fmaxf(fmaxf(mA[0], mA[1]), fmaxf(mA[2], mA[3]));
            m = fmaxf(m, __shfl_xor(m, 32));
            float m2 = m * LOG2E;

            float sm0 = 0.f, sm1 = 0.f, sm2 = 0.f, sm3 = 0.f;
#pragma unroll
            for (int t = 0; t < 4; ++t)
#pragma unroll
                for (int r = 0; r < 16; ++r) {
                    float p = vexp2(__builtin_fmaf(s[t][r], LOG2E, -m2));
                    s[t][r] = p;
                    if (t == 0) sm0 += p; else if (t == 1) sm1 += p;
                    else if (t == 2) sm2 += p; else sm3 += p;
                }
            float sum = (sm0 + sm1) + (sm2 + sm3);
            sum += __shfl_xor(sum, 32);
            float inv = 1.f / sum;

            f32x16 o0 = {}, o1 = {};
#pragma unroll
            for (int c = 0; c < 8; ++c) {
                int t = c >> 1, hf = (c & 1) * 8;
                u32 x0 = cvtpk(s[t][hf + 0], s[t][hf + 1]);
                u32 x1 = cvtpk(s[t][hf + 2], s[t][hf + 3]);
                u32 y0 = cvtpk(s[t][hf + 4], s[t][hf + 5]);
                u32 y1 = cvtpk(s[t][hf + 6], s[t][hf + 7]);
                plswap(x0, y0);
                plswap(x1, y1);
                union { u32 wd[4]; bf16x8 v; } pb;
                pb.wd[0] = x0; pb.wd[1] = x1; pb.wd[2] = y0; pb.wd[3] = y1;
                bf16x8 va = *reinterpret_cast<const bf16x8*>(
                    &Vs[h * 2176 + (lo2 & 15) * 136 + c * 16 + hi2 * 8]);
                if (c & 1)
                    o1 = __builtin_amdgcn_mfma_f32_32x32x16_bf16(va, pb.v, o1, 0, 0, 0);
                else
                    o0 = __builtin_amdgcn_mfma_f32_32x32x16_bf16(va, pb.v, o0, 0, 0, 0);
            }

            int tok = qt * 32 + lo2;
            u32 off0 = (u32)(tok * 256 + h * 32 + 8 * hi2) ^ ((tok & 7) << 4);
            u32 off1 = (u32)(tok * 256 + h * 32 + 16 + 8 * hi2) ^ ((tok & 7) << 4);
            uint2 p0, p1;
            p0.x = cvtpk((o0[0] + o1[0]) * inv, (o0[1] + o1[1]) * inv);
            p0.y = cvtpk((o0[2] + o1[2]) * inv, (o0[3] + o1[3]) * inv);
            p1.x = cvtpk((o0[4] + o1[4]) * inv, (o0[5] + o1[5]) * inv);
            p1.y = cvtpk((o0[6] + o1[6]) * inv, (o0[7] + o1[7]) * inv);
            *reinterpret_cast<uint2*>(ctxs + off0) = p0;
            *reinterpret_cast<uint2*>(ctxs + off1) = p1;
        }
    }
    __syncthreads();   // all phase-3 reads of Qs/Ks/Vs complete; ctx ready

    // ---- Phase 3.5: stashed Wo regs -> bf16 into dead Ks region.
    // Thread owns (n, k0..k0+3): one packed 8B store at byte
    // (n*256 + k0*2) ^ ((n&7)<<4). Within a wave n is 64 consecutive ->
    // 8 bank-pair classes (~8-way) vs r16's 16-way x 4 scalar stores.
#pragma unroll
    for (int i = 0; i < 8; ++i) {
        int idx = i * 512 + tid;
        int n = idx & 127;
        int k0 = (idx >> 7) * 4;
        uint2 pw;
        pw.x = cvtpk(wpre[i][0], wpre[i][1]);
        pw.y = cvtpk(wpre[i][2], wpre[i][3]);
        *reinterpret_cast<uint2*>(wob + ((u32)(n * 256 + k0 * 2) ^ ((n & 7) << 4))) = pw;
    }
    __syncthreads();   // wo_lds ready for all waves

    // ---- Phase 4: out-proj; wave h does tokens [h*16, h*16+16).
    // B fragments from swizzled LDS; row (c*16+lo) has (row&7) == (lo&7).
    {
        f32x4 acc[8];
#pragma unroll
        for (int c = 0; c < 8; ++c) acc[c] = f32x4{0.f, 0.f, 0.f, 0.f};
#pragma unroll
        for (int kk = 0; kk < 4; ++kk) {
            int tokrow = h * 16 + lo;
            u32 aoff = (u32)(tokrow * 256 + kk * 64 + hi * 16) ^ ((tokrow & 7) << 4);
            bf16x8 a = *reinterpret_cast<const bf16x8*>(ctxs + aoff);
#pragma unroll
            for (int c = 0; c < 8; ++c) {
                u32 boff = (u32)((c * 16 + lo) * 256 + kk * 64 + hi * 16) ^ ((lo & 7) << 4);
                bf16x8 b = *reinterpret_cast<const bf16x8*>(wob + boff);
                acc[c] = __builtin_amdgcn_mfma_f32_16x16x32_bf16(a, b, acc[c], 0, 0, 0);
            }
        }
#pragma unroll
        for (int c = 0; c < 8; ++c) {
            int col = c * 16 + lo;
            float bval = bo[col];
#pragma unroll
            for (int j = 0; j < 4; ++j) {
                int t = seq * 128 + h * 16 + hi * 4 + j;
                out[(size_t)t * EMB + col] = (acc[c][j] + bval) * mask[t];
            }
        }
    }
}

// ---------------------------------------------------------------------------
extern "C" void kernel_launch(void* const* d_in, const int* in_sizes, int n_in,
                              void* d_out, int out_size, void* d_ws, size_t ws_size,
                              hipStream_t stream) {
    const float* pe   = (const float*)d_in[0];
    const float* mask = (const float*)d_in[1];
    const float* ln_g = (const float*)d_in[2];
    const float* ln_b = (const float*)d_in[3];
    const float* wq   = (const float*)d_in[4];
    const float* bq   = (const float*)d_in[5];
    const float* wk   = (const float*)d_in[6];
    const float* bk   = (const float*)d_in[7];
    const float* wv   = (const float*)d_in[8];
    const float* bv   = (const float*)d_in[9];
    const float* wo   = (const float*)d_in[10];
    const float* bo   = (const float*)d_in[11];
    float* out = (float*)d_out;

    hipLaunchKernelGGL(k_fused, dim3(256), dim3(512), 0, stream, pe, ln_g, ln_b,
                       wq, wk, wv, wo, bq, bk, bv, bo, mask, out);
}